// Round 5
// baseline (25424.869 us; speedup 1.0000x reference)
//
#include <hip/hip_runtime.h>

// B=64, T=256, H=1024, L=6. Cell: h = tanh((prev + h_old) @ W^T + b1 + b2).
// v5: W REGISTER-stationary. 8 groups (8 batches) x 32 j-slice blocks = 256
// blocks/CUs. Thread (jl,ks) holds W[q*32+jl][ks*128:+128] in 32 float4 VGPRs
// (static indices -> no scratch). Inner loop: 1024 reg-reg FMA into 8 indep
// accumulators + 256 broadcast ds_read_b128. Cross-thread k-reduce via
// shfl_xor(32) + 4KB LDS. Barrier: per-block monotonic flag (release store),
// 32-lane relaxed poll + single acquire load (no RMW contention).

#define BB 64
#define TT 256
#define HH 1024
#define LL 6
#define NG 8     // groups, GB batches each
#define GB 8     // batches per group
#define NQ 32    // blocks (j-slices) per group
#define SJ 32    // j rows per block
#define NTH 256

#define HSTATE_FLOATS (2ull * BB * LL * HH)            // parity x b x l x k
#define FLAGS_OFF   (HSTATE_FLOATS * 4)                // 3,145,728 B
#define FLAGS_BYTES ((size_t)NG * NQ * 4)              // 1 KB (monotonic flags)
#define PARTIAL_OFF (FLAGS_OFF + 1024)                 // [2][BB][NQ] floats

__global__ void __launch_bounds__(NTH, 1)
rnn_kernel(const float* __restrict__ h0,
           const float* __restrict__ Whh,
           const float* __restrict__ bias_ih,
           const float* __restrict__ bias_bh,
           const float* __restrict__ w_out,
           const float* __restrict__ b_out,
           float* hstate, unsigned* flags, float* partial,
           float* __restrict__ d_out)
{
    __shared__ float4 s4[GB * 256];      // 32 KB: s[bb][k4], full 8b x 1024k
    __shared__ float  pred[4][SJ][GB];   //  4 KB: per-wave partials

    const int tid = threadIdx.x;
    const int g   = blockIdx.x & 7;      // group
    const int q   = blockIdx.x >> 3;     // j-slice 0..31
    const int gb  = g * GB;
    const int jl  = tid & 31;
    const int ks  = tid >> 5;            // k-slice 0..7
    const int wv  = tid >> 6;            // wave 0..3
    const int jg  = q * SJ + jl;

    // ---- W -> registers (one-time, uncoalesced gather is fine)
    float4 wreg[32];
    {
        const float4* wrow = (const float4*)(Whh + (size_t)jg * HH) + ks * 32;
#pragma unroll
        for (int r = 0; r < 32; ++r) wreg[r] = wrow[r];
    }

    const float bias_j = bias_ih[jg] + bias_bh[jg];
    const float wout_j = w_out[jg];
    const float bout   = b_out[0];

    // ---- init parity-1 hstate: block covers k in [q*32, q*32+32)
    {
        int bb = tid >> 5, k = q * SJ + (tid & 31);
#pragma unroll
        for (int l = 0; l < LL; ++l)
            hstate[(((size_t)1 * BB + gb + bb) * LL + l) * HH + k] =
                h0[((size_t)l * BB + gb + bb) * HH + k];
    }

    unsigned* gflags = flags + g * NQ;
    unsigned barno = 0;

    auto gbar = [&]() {
        ++barno;
        __syncthreads();                 // all block stores issued & acked
        if (tid == 0)
            __hip_atomic_store(gflags + q, barno, __ATOMIC_RELEASE,
                               __HIP_MEMORY_SCOPE_AGENT);
        if (tid < 64) {                  // wave 0: vector poll, no contention
            for (int w = 0; w < 30000; ++w) {
                unsigned v = (tid < NQ)
                    ? __hip_atomic_load(gflags + tid, __ATOMIC_RELAXED,
                                        __HIP_MEMORY_SCOPE_AGENT)
                    : barno;
                if (!~__ballot(v >= barno)) break;
            }
            if (tid == 0)                // acquire: order + invalidate caches
                (void)__hip_atomic_load(gflags + q, __ATOMIC_ACQUIRE,
                                        __HIP_MEMORY_SCOPE_AGENT);
        }
        __syncthreads();
    };

    gbar();   // publish init

    for (int t = 0; t < TT; ++t) {
        const int pw = t & 1, pr = pw ^ 1;
        for (int l = 0; l < LL; ++l) {
            const int lp = (l == 0) ? (LL - 1) : (l - 1);
            const int pp = (l == 0) ? pr : pw;   // prev-chain parity

            // ---- stage s = prev + h_old (issue all 16 loads, then add+write)
            const float* baseP = hstate + (((size_t)pp * BB + gb) * LL + lp) * HH;
            const float* baseH = hstate + (((size_t)pr * BB + gb) * LL + l ) * HH;
            float4 pa[8], ha[8];
#pragma unroll
            for (int r = 0; r < 8; ++r) {        // r = batch, tid = k4 (coalesced)
                pa[r] = *(const float4*)(baseP + (size_t)r * LL * HH + tid * 4);
                ha[r] = *(const float4*)(baseH + (size_t)r * LL * HH + tid * 4);
            }
#pragma unroll
            for (int r = 0; r < 8; ++r)
                s4[r * 256 + tid] = make_float4(pa[r].x + ha[r].x, pa[r].y + ha[r].y,
                                                pa[r].z + ha[r].z, pa[r].w + ha[r].w);
            __syncthreads();

            // ---- 1024 reg-reg FMA, 8 independent accumulator chains
            float acc[GB];
#pragma unroll
            for (int b = 0; b < GB; ++b) acc[b] = 0.f;
            const float4* xbase = s4 + ks * 32;
#pragma unroll
            for (int b = 0; b < GB; ++b) {
#pragma unroll
                for (int k4 = 0; k4 < 32; ++k4) {
                    float4 x = xbase[b * 256 + k4];   // broadcast LDS read
                    float4 w = wreg[k4];              // register-resident W
                    acc[b] = fmaf(w.x, x.x, fmaf(w.y, x.y,
                             fmaf(w.z, x.z, fmaf(w.w, x.w, acc[b]))));
                }
            }

            // ---- k-reduce: merge ks-pairs in-wave, then 4 waves via LDS
#pragma unroll
            for (int b = 0; b < GB; ++b) acc[b] += __shfl_xor(acc[b], 32);
            if ((tid & 63) < 32) {
                float4* pr4 = (float4*)&pred[wv][jl][0];
                pr4[0] = make_float4(acc[0], acc[1], acc[2], acc[3]);
                pr4[1] = make_float4(acc[4], acc[5], acc[6], acc[7]);
            }
            __syncthreads();

            const int bb = tid >> 5;     // now: thread (jl, bb) owns output
            float ysum = pred[0][jl][bb] + pred[1][jl][bb]
                       + pred[2][jl][bb] + pred[3][jl][bb];
            float y = tanhf(ysum + bias_j);
            hstate[(((size_t)pw * BB + gb + bb) * LL + l) * HH + jg] = y;

            if (l == LL - 1) {
                float c = y * wout_j;
#pragma unroll
                for (int off = 16; off; off >>= 1) c += __shfl_down(c, off, 32);
                if (jl == 0)
                    partial[(size_t)pw * BB * NQ + (size_t)(gb + bb) * NQ + q] = c;
            }
            if (t == TT - 1)
                d_out[(size_t)BB * TT + ((size_t)l * BB + gb + bb) * HH + jg] = y;

            gbar();

            if (l == LL - 1 && q == 0 && tid < GB) {
                int bo = gb + tid;
                float s = bout;
#pragma unroll
                for (int qq = 0; qq < NQ; ++qq)
                    s += partial[(size_t)pw * BB * NQ + (size_t)bo * NQ + qq];
                d_out[(size_t)bo * TT + t] = s;    // out[b, t, 0]
            }
        }
    }
}

extern "C" void kernel_launch(void* const* d_in, const int* in_sizes, int n_in,
                              void* d_out, int out_size, void* d_ws, size_t ws_size,
                              hipStream_t stream) {
    // inputs: 0:x(unused) 1:h0 2:weight_ih(unused) 3:bias_ih 4:weight_hh 5:bias_bh 6:w_out 7:b_out
    const float* h0      = (const float*)d_in[1];
    const float* bias_ih = (const float*)d_in[3];
    const float* Whh     = (const float*)d_in[4];
    const float* bias_bh = (const float*)d_in[5];
    const float* w_out   = (const float*)d_in[6];
    const float* b_out   = (const float*)d_in[7];

    float*    hstate  = (float*)d_ws;
    unsigned* flags   = (unsigned*)((char*)d_ws + FLAGS_OFF);
    float*    partial = (float*)((char*)d_ws + PARTIAL_OFF);

    hipMemsetAsync(flags, 0, FLAGS_BYTES, stream);   // fresh monotonic flags per launch
    rnn_kernel<<<NG * NQ, NTH, 0, stream>>>(h0, Whh, bias_ih, bias_bh,
                                            w_out, b_out, hstate, flags, partial,
                                            (float*)d_out);
}

// Round 6
// 18179.903 us; speedup vs baseline: 1.3985x; 1.3985x over previous
//
#include <hip/hip_runtime.h>

// B=64, T=256, H=1024, L=6. Cell: h = tanh((prev + h_old) @ W^T + b1 + b2).
// v6: same topology as v5 (8 groups x 8 batches x 32 j-slice blocks, W in
// VGPRs), but ALL cross-block communication uses RELAXED agent-scope atomics
// (per-access MALL-coherent) and the barrier has NO release/acquire fences.
// Round-5 counters showed WRITE_SIZE=830MB: the per-cell release/acquire was
// emitting buffer_wbl2/buffer_inv (full L2 flush+inv per cell) -> HBM churn.
// Ordering: stores -> s_waitcnt vmcnt(0) (per wave) -> __syncthreads ->
// relaxed flag store -> relaxed vector poll -> compiler barrier -> atomic loads.

#define BB 64
#define TT 256
#define HH 1024
#define LL 6
#define NG 8     // groups, GB batches each
#define GB 8     // batches per group
#define NQ 32    // blocks (j-slices) per group
#define SJ 32    // j rows per block
#define NTH 256

#define HSTATE_FLOATS (2ull * BB * LL * HH)            // parity x b x l x k
#define FLAGS_OFF   (HSTATE_FLOATS * 4)                // 3,145,728 B
#define FLAGS_BYTES ((size_t)NG * NQ * 4)              // 1 KB monotonic flags
#define PARTIAL_OFF (FLAGS_OFF + 1024)                 // [2][BB][NQ] floats

__device__ __forceinline__ float2 aload2(const float* p) {
    unsigned long long u = __hip_atomic_load((const unsigned long long*)p,
                                             __ATOMIC_RELAXED, __HIP_MEMORY_SCOPE_AGENT);
    union { unsigned long long u; float2 f; } c; c.u = u; return c.f;
}
__device__ __forceinline__ float aload1(const float* p) {
    return __hip_atomic_load(p, __ATOMIC_RELAXED, __HIP_MEMORY_SCOPE_AGENT);
}
__device__ __forceinline__ void astore1(float* p, float v) {
    __hip_atomic_store(p, v, __ATOMIC_RELAXED, __HIP_MEMORY_SCOPE_AGENT);
}

__global__ void __launch_bounds__(NTH, 1)
rnn_kernel(const float* __restrict__ h0,
           const float* __restrict__ Whh,
           const float* __restrict__ bias_ih,
           const float* __restrict__ bias_bh,
           const float* __restrict__ w_out,
           const float* __restrict__ b_out,
           float* hstate, unsigned* flags, float* partial,
           float* __restrict__ d_out)
{
    __shared__ float4 s4[GB * 256];       // 32 KB: s[bb][k4]
    __shared__ float  pred[4][SJ][10];    //  5 KB: per-wave partials (pad 10)

    const int tid = threadIdx.x;
    const int g   = blockIdx.x & 7;       // group
    const int q   = blockIdx.x >> 3;      // j-slice 0..31
    const int gb  = g * GB;
    const int jl  = tid & 31;
    const int ks  = tid >> 5;             // k-slice 0..7
    const int wv  = tid >> 6;             // wave 0..3
    const int jg  = q * SJ + jl;

    // ---- W -> registers (one-time)
    float4 wreg[32];
    {
        const float4* wrow = (const float4*)(Whh + (size_t)jg * HH) + ks * 32;
#pragma unroll
        for (int r = 0; r < 32; ++r) wreg[r] = wrow[r];
    }

    const float bias_j = bias_ih[jg] + bias_bh[jg];
    const float wout_j = w_out[jg];
    const float bout   = b_out[0];

    // ---- init parity-1 hstate (atomic stores: cross-block visible)
    {
        int bb = tid >> 5, k = q * SJ + (tid & 31);
#pragma unroll
        for (int l = 0; l < LL; ++l)
            astore1(&hstate[(((size_t)1 * BB + gb + bb) * LL + l) * HH + k],
                    h0[((size_t)l * BB + gb + bb) * HH + k]);
    }

    unsigned* gflags = flags + g * NQ;
    unsigned barno = 0;

    auto gbar = [&]() {
        ++barno;
        asm volatile("s_waitcnt vmcnt(0)" ::: "memory");  // this wave's stores done
        __syncthreads();                                  // => all waves' stores done
        if (tid == 0)
            __hip_atomic_store(gflags + q, barno, __ATOMIC_RELAXED,
                               __HIP_MEMORY_SCOPE_AGENT);
        if (tid < 64) {                                   // wave-0 vector poll
            for (int w = 0; w < 100000; ++w) {
                unsigned v = (tid < NQ)
                    ? __hip_atomic_load(gflags + tid, __ATOMIC_RELAXED,
                                        __HIP_MEMORY_SCOPE_AGENT)
                    : barno;
                if (!~__ballot(v >= barno)) break;
                __builtin_amdgcn_s_sleep(1);              // throttle MALL hammering
            }
        }
        __syncthreads();
        asm volatile("" ::: "memory");                    // no hoisting of data loads
    };

    gbar();   // publish init

    for (int t = 0; t < TT; ++t) {
        const int pw = t & 1, pr = pw ^ 1;
        for (int l = 0; l < LL; ++l) {
            const int lp = (l == 0) ? (LL - 1) : (l - 1);
            const int pp = (l == 0) ? pr : pw;   // prev-chain parity

            // ---- stage s = prev + h_old via MALL-coherent relaxed loads
            const float* baseP = hstate + (((size_t)pp * BB + gb) * LL + lp) * HH;
            const float* baseH = hstate + (((size_t)pr * BB + gb) * LL + l ) * HH;
            float2 pa[GB][2], ha[GB][2];
#pragma unroll
            for (int r = 0; r < GB; ++r) {       // r = batch, tid = k4 (coalesced)
                const float* P = baseP + (size_t)r * LL * HH + tid * 4;
                const float* H = baseH + (size_t)r * LL * HH + tid * 4;
                pa[r][0] = aload2(P);  pa[r][1] = aload2(P + 2);
                ha[r][0] = aload2(H);  ha[r][1] = aload2(H + 2);
            }
#pragma unroll
            for (int r = 0; r < GB; ++r)
                s4[r * 256 + tid] = make_float4(pa[r][0].x + ha[r][0].x,
                                                pa[r][0].y + ha[r][0].y,
                                                pa[r][1].x + ha[r][1].x,
                                                pa[r][1].y + ha[r][1].y);
            __syncthreads();

            // ---- 1024 reg-reg FMA, 8 independent accumulator chains
            float acc[GB];
#pragma unroll
            for (int b = 0; b < GB; ++b) acc[b] = 0.f;
            const float4* xbase = s4 + ks * 32;
#pragma unroll
            for (int b = 0; b < GB; ++b) {
#pragma unroll
                for (int k4 = 0; k4 < 32; ++k4) {
                    float4 x = xbase[b * 256 + k4];   // broadcast LDS read
                    float4 w = wreg[k4];              // register-resident W
                    acc[b] = fmaf(w.x, x.x, fmaf(w.y, x.y,
                             fmaf(w.z, x.z, fmaf(w.w, x.w, acc[b]))));
                }
            }

            // ---- k-reduce: shfl merge ks pairs, then 4 waves via LDS
#pragma unroll
            for (int b = 0; b < GB; ++b) acc[b] += __shfl_xor(acc[b], 32);
            if ((tid & 63) < 32) {
#pragma unroll
                for (int b = 0; b < GB; ++b) pred[wv][jl][b] = acc[b];
            }
            __syncthreads();

            const int bb = tid >> 5;     // thread (jl, bb) owns output
            float ysum = pred[0][jl][bb] + pred[1][jl][bb]
                       + pred[2][jl][bb] + pred[3][jl][bb];
            float y = tanhf(ysum + bias_j);
            astore1(&hstate[(((size_t)pw * BB + gb + bb) * LL + l) * HH + jg], y);

            if (l == LL - 1) {
                float c = y * wout_j;
#pragma unroll
                for (int off = 16; off; off >>= 1) c += __shfl_down(c, off, 32);
                if (jl == 0)
                    astore1(&partial[(size_t)pw * BB * NQ + (size_t)(gb + bb) * NQ + q], c);
            }
            if (t == TT - 1)
                d_out[(size_t)BB * TT + ((size_t)l * BB + gb + bb) * HH + jg] = y;

            gbar();

            if (l == LL - 1 && q == 0 && tid < GB) {
                int bo = gb + tid;
                float s = bout;
#pragma unroll
                for (int qq = 0; qq < NQ; ++qq)
                    s += aload1(&partial[(size_t)pw * BB * NQ + (size_t)bo * NQ + qq]);
                d_out[(size_t)bo * TT + t] = s;    // out[b, t, 0]
            }
        }
    }
}

extern "C" void kernel_launch(void* const* d_in, const int* in_sizes, int n_in,
                              void* d_out, int out_size, void* d_ws, size_t ws_size,
                              hipStream_t stream) {
    // inputs: 0:x(unused) 1:h0 2:weight_ih(unused) 3:bias_ih 4:weight_hh 5:bias_bh 6:w_out 7:b_out
    const float* h0      = (const float*)d_in[1];
    const float* bias_ih = (const float*)d_in[3];
    const float* Whh     = (const float*)d_in[4];
    const float* bias_bh = (const float*)d_in[5];
    const float* w_out   = (const float*)d_in[6];
    const float* b_out   = (const float*)d_in[7];

    float*    hstate  = (float*)d_ws;
    unsigned* flags   = (unsigned*)((char*)d_ws + FLAGS_OFF);
    float*    partial = (float*)((char*)d_ws + PARTIAL_OFF);

    hipMemsetAsync(flags, 0, FLAGS_BYTES, stream);   // fresh monotonic flags per launch
    rnn_kernel<<<NG * NQ, NTH, 0, stream>>>(h0, Whh, bias_ih, bias_bh,
                                            w_out, b_out, hstate, flags, partial,
                                            (float*)d_out);
}